// Round 14
// baseline (255.032 us; speedup 1.0000x reference)
//
#include <hip/hip_runtime.h>

#define NEG_SLOPE 0.2f
#define CAP 64  // per-node edge bucket capacity (Poisson(16)+selfloop; P(overflow)~1e-19)
#define LOG2E 1.44269504f

typedef short bf16x4 __attribute__((ext_vector_type(4)));
typedef short bf16x8 __attribute__((ext_vector_type(8)));
typedef float f32x4 __attribute__((ext_vector_type(4)));
typedef _Float16 half4v __attribute__((ext_vector_type(4)));
typedef _Float16 half8v __attribute__((ext_vector_type(8)));

// fp32 -> bf16 round-to-nearest-even
__device__ inline short bf16_rne(float x) {
    unsigned u = __float_as_uint(x);
    unsigned r = u + 0x7FFFu + ((u >> 16) & 1u);
    return (short)(r >> 16);
}

__device__ inline float fast_exp2(float x) {
#if __has_builtin(__builtin_amdgcn_exp2f)
    return __builtin_amdgcn_exp2f(x);
#else
    return exp2f(x);
#endif
}

// ---------------- prep: W1^T bf16, W2^T fp16, bucket init (cursor=1, self-loop slot 0) -------
// Coalesced-read transpose (R10 form).

__global__ void k_prepw(const float* __restrict__ W1, short* __restrict__ Wt,
                        const float* __restrict__ W2, _Float16* __restrict__ W2t,
                        int* __restrict__ cursor, int* __restrict__ col, int N) {
    int r = blockIdx.x;          // 0..255 (row of W1)
    int t = threadIdx.x;         // 0..255 (col of W1)
    Wt[(size_t)t * 256 + r] = bf16_rne(W1[(size_t)r * 256 + t]);
    if (t < 32) W2t[(size_t)t * 256 + r] = (_Float16)W2[(size_t)r * 32 + t];
    int gid = blockIdx.x * 256 + threadIdx.x;
    if (gid < N) {
        cursor[gid] = 1;                 // self-loop pre-counted
        col[(size_t)gid * CAP] = gid;    // self-loop in slot 0
    }
}

// ---------------- fused GEMM1 + scatter: k-loop-paced atomics, BM=32 (R13) -------------------
// R12 (BM=64, 782 blocks) measured 72.6us at 24% occupancy — grid-limited to ~3 blocks/CU
// while LDS allows 6. R13 halves the M-tile: 1563 blocks, 22.5KB LDS -> whole grid
// co-resident (~24 waves/CU), 2x atomic MLP and 2x gemm TLP. Scatter = 2 edges/thread,
// paced at k-iters {0:atomic e0, 1:store e0, 4:atomic e1, 5:store e1} (R12-proven spacing).

__global__ __launch_bounds__(256) void k_gemm1_scatter(
        const float* __restrict__ x, const short* __restrict__ Wt,
        const float* __restrict__ a_src, const float* __restrict__ a_dst,
        _Float16* __restrict__ h1, float* __restrict__ as1, float* __restrict__ ad1, int N,
        const int* __restrict__ srcI, const int* __restrict__ dstI,
        int* __restrict__ cursor, int* __restrict__ col, int E) {
    __shared__ short Ab[32 * 40];   // [m][k], stride 40
    __shared__ short Bb[256 * 40];  // [n][k], stride 40
    const int tid = threadIdx.x;
    const int b = blockIdx.x;
    const int nGemm = gridDim.x;

    // ---- scatter slice: load 2 edges/thread now (plain loads, no atomics) ----
    const int chunk = (E + nGemm - 1) / nGemm;      // 512 for E=800k, 1563 blocks
    const int ss = b * chunk;
    const int se = (ss + chunk < E) ? (ss + chunk) : E;
    const int jb = ss + tid * 2;
    int2 d2 = make_int2(0, 0), s2 = make_int2(0, 0);
    int p0 = CAP, p1 = CAP;
    const bool pair = (jb + 1 < se);
    if (pair) {
        d2 = *(const int2*)(dstI + jb);
        s2 = *(const int2*)(srcI + jb);
    } else if (jb < se) {
        // ragged tail: scalar, immediate
        for (int i = jb; i < se; ++i) {
            int d = dstI[i];
            int p = atomicAdd(&cursor[d], 1);
            if (p < CAP) col[(size_t)d * CAP + p] = srcI[i];
        }
    }

    // ---- GEMM tile (BM=32) with paced scatter ops ----
    const int lane = tid & 63;
    const int wc = tid >> 6;             // wave index == head
    const int row0 = b * 32;
    const int m15 = lane & 15, quad4 = lane >> 4;

    f32x4 acc[2][4] = {};

    const int arow = tid >> 3;           // 0..31
    const int akseg = (tid & 7) * 4;     // 0,4,...,28

#pragma unroll
    for (int kk = 0; kk < 8; ++kk) {
        const int k0 = kk * 32;
        {
            int row = row0 + arow;
            float vals[4];
            if (row < N) {
                float4 v0 = *(const float4*)(x + (size_t)row * 256 + k0 + akseg);
                vals[0] = v0.x; vals[1] = v0.y; vals[2] = v0.z; vals[3] = v0.w;
            } else {
#pragma unroll
                for (int i = 0; i < 4; ++i) vals[i] = 0.f;
            }
            short buf[4];
#pragma unroll
            for (int i = 0; i < 4; ++i) buf[i] = bf16_rne(vals[i]);
            *(bf16x4*)&Ab[arow * 40 + akseg] = *(bf16x4*)&buf[0];
        }
        {
#pragma unroll
            for (int s = 0; s < 4; ++s)
                *(bf16x8*)&Bb[tid * 40 + s * 8] =
                    *(const bf16x8*)(Wt + (size_t)tid * 256 + k0 + s * 8);
        }
        // paced scatter: atomic e0 @kk0, store e0 @kk1, atomic e1 @kk4, store e1 @kk5.
        // kk compile-time (full unroll) -> straight-line, no runtime-indexed regs.
        if (pair) {
            if (kk == 0) {
                p0 = atomicAdd(&cursor[d2.x], 1);
            } else if (kk == 1) {
                if (p0 < CAP) col[(size_t)d2.x * CAP + p0] = s2.x;
            } else if (kk == 4) {
                p1 = atomicAdd(&cursor[d2.y], 1);
            } else if (kk == 5) {
                if (p1 < CAP) col[(size_t)d2.y * CAP + p1] = s2.y;
            }
        }
        __syncthreads();
        bf16x8 ab[2];
#pragma unroll
        for (int mt = 0; mt < 2; ++mt)
            ab[mt] = *(const bf16x8*)&Ab[(mt * 16 + m15) * 40 + quad4 * 8];
#pragma unroll
        for (int nt = 0; nt < 4; ++nt) {
            int nn = wc * 64 + nt * 16 + m15;
            bf16x8 bb = *(const bf16x8*)&Bb[nn * 40 + quad4 * 8];
#pragma unroll
            for (int mt = 0; mt < 2; ++mt)
                acc[mt][nt] = __builtin_amdgcn_mfma_f32_16x16x32_bf16(ab[mt], bb, acc[mt][nt], 0, 0, 0);
        }
        __syncthreads();
    }
    const int head = wc;
#pragma unroll
    for (int mt = 0; mt < 2; ++mt) {
        float va[4] = {0.f, 0.f, 0.f, 0.f};
        float vd[4] = {0.f, 0.f, 0.f, 0.f};
#pragma unroll
        for (int nt = 0; nt < 4; ++nt) {
            int colg = wc * 64 + nt * 16 + m15;
            float asv = a_src[colg];
            float adv = a_dst[colg];
#pragma unroll
            for (int r = 0; r < 4; ++r) {
                float accv = acc[mt][nt][r];
                int row = row0 + mt * 16 + quad4 * 4 + r;
                if (row < N) h1[(size_t)row * 256 + colg] = (_Float16)accv;
                va[r] = fmaf(accv, asv, va[r]);
                vd[r] = fmaf(accv, adv, vd[r]);
            }
        }
#pragma unroll
        for (int r = 0; r < 4; ++r) {
#pragma unroll
            for (int mq = 1; mq < 16; mq <<= 1) {
                va[r] += __shfl_xor(va[r], mq);
                vd[r] += __shfl_xor(vd[r], mq);
            }
            int row = row0 + mt * 16 + quad4 * 4 + r;
            if (m15 == 0 && row < N) {
                as1[(size_t)row * 4 + head] = va[r] * LOG2E;   // pre-scaled for exp2
                ad1[(size_t)row * 4 + head] = vd[r] * LOG2E;
            }
        }
    }
}

// ---------------- fused gather1 + GEMM2 + alpha2 (R1-verified inner loop, best measured:
// 69.9 us. Memory-bound on the h1 gather stream (R8: VALU cuts don't help) — keep simple). ----

__global__ __launch_bounds__(256) void k_fuse1(
        const _Float16* __restrict__ h1, const float* __restrict__ as1,
        const float* __restrict__ ad1, const int* __restrict__ cursor,
        const int* __restrict__ col, const float* __restrict__ b1,
        const _Float16* __restrict__ W2t, const float* __restrict__ a_s2,
        const float* __restrict__ a_d2, _Float16* __restrict__ z,
        float* __restrict__ as2, float* __restrict__ ad2, int N) {
    __shared__ _Float16 W2s[32 * 264];   // [c][k], pad 8 shorts (16B) per row
    __shared__ _Float16 h2s[4 * 256];    // per-wave h2 slot
    const int tid = threadIdx.x;
    const int l = tid & 63;
    const int wave = tid >> 6;
    const int n = blockIdx.x * 4 + wave;

    for (int i8 = tid; i8 < 1024; i8 += 256) {
        int elem = i8 * 8;
        int row = elem >> 8, k = elem & 255;
        *(half8v*)&W2s[row * 264 + k] = *(const half8v*)(W2t + (size_t)row * 256 + k);
    }
    __syncthreads();
    if (n >= N) return;

    const int head = l >> 4;
    const int beg = n * CAP;
    int deg = __builtin_amdgcn_readfirstlane(cursor[n]);
    if (deg > CAP) deg = CAP;
    // whole bucket in one coalesced load; per-edge index comes from readlane (register)
    int colv = 0;
    if (l < deg) colv = col[beg + l];
    float adv = ad1[(size_t)n * 4 + head];

    f32x4 a0 = {}, a1 = {}, a2 = {}, a3 = {};
    float s0 = 0.f, s1 = 0.f, s2 = 0.f, s3 = 0.f;
    int j = 0;
    for (; j + 3 < deg; j += 4) {
        int c0 = __builtin_amdgcn_readlane(colv, j);
        int c1 = __builtin_amdgcn_readlane(colv, j + 1);
        int c2 = __builtin_amdgcn_readlane(colv, j + 2);
        int c3 = __builtin_amdgcn_readlane(colv, j + 3);
        float e0 = as1[(size_t)c0 * 4 + head] + adv;
        float e1 = as1[(size_t)c1 * 4 + head] + adv;
        float e2 = as1[(size_t)c2 * 4 + head] + adv;
        float e3 = as1[(size_t)c3 * 4 + head] + adv;
        e0 = fmaxf(e0, NEG_SLOPE * e0); e1 = fmaxf(e1, NEG_SLOPE * e1);
        e2 = fmaxf(e2, NEG_SLOPE * e2); e3 = fmaxf(e3, NEG_SLOPE * e3);
        float p0 = fast_exp2(e0), p1 = fast_exp2(e1);
        float p2 = fast_exp2(e2), p3 = fast_exp2(e3);
        half4v h0 = *((const half4v*)(h1 + (size_t)c0 * 256) + l);
        half4v hv1 = *((const half4v*)(h1 + (size_t)c1 * 256) + l);
        half4v h2 = *((const half4v*)(h1 + (size_t)c2 * 256) + l);
        half4v h3 = *((const half4v*)(h1 + (size_t)c3 * 256) + l);
        s0 += p0; s1 += p1; s2 += p2; s3 += p3;
        a0 += __builtin_convertvector(h0, f32x4) * p0;
        a1 += __builtin_convertvector(hv1, f32x4) * p1;
        a2 += __builtin_convertvector(h2, f32x4) * p2;
        a3 += __builtin_convertvector(h3, f32x4) * p3;
    }
    for (; j < deg; ++j) {
        int c0 = __builtin_amdgcn_readlane(colv, j);
        float e0 = as1[(size_t)c0 * 4 + head] + adv;
        e0 = fmaxf(e0, NEG_SLOPE * e0);
        float p0 = fast_exp2(e0);
        half4v h0 = *((const half4v*)(h1 + (size_t)c0 * 256) + l);
        s0 += p0;
        a0 += __builtin_convertvector(h0, f32x4) * p0;
    }
    f32x4 at = (a0 + a1) + (a2 + a3);
    float iv = 1.f / ((s0 + s1) + (s2 + s3) + 1e-16f);
    float4 bb = *(const float4*)(b1 + l * 4);
    float4 v;
    v.x = at[0] * iv + bb.x;
    v.y = at[1] * iv + bb.y;
    v.z = at[2] * iv + bb.z;
    v.w = at[3] * iv + bb.w;
    v.x = (v.x > 0.f) ? v.x : (__expf(v.x) - 1.f);
    v.y = (v.y > 0.f) ? v.y : (__expf(v.y) - 1.f);
    v.z = (v.z > 0.f) ? v.z : (__expf(v.z) - 1.f);
    v.w = (v.w > 0.f) ? v.w : (__expf(v.w) - 1.f);
    half4v hv;
    hv.x = (_Float16)v.x; hv.y = (_Float16)v.y; hv.z = (_Float16)v.z; hv.w = (_Float16)v.w;
    *((half4v*)(h2s + wave * 256) + l) = hv;   // same-wave LDS, no barrier needed

    // GEMM2 row: lane l -> channel c = l&31, k-half kh = (l>>5)*128
    int c = l & 31;
    int kh = (l >> 5) * 128;
    const _Float16* hrow = h2s + wave * 256 + kh;
    const _Float16* wrow = W2s + c * 264 + kh;
    float accz = 0.f;
#pragma unroll
    for (int k = 0; k < 128; k += 8) {
        half8v hz = *(const half8v*)(hrow + k);
        half8v wz = *(const half8v*)(wrow + k);
#if __has_builtin(__builtin_amdgcn_fdot2)
        accz = __builtin_amdgcn_fdot2(__builtin_shufflevector(hz, hz, 0, 1),
                                      __builtin_shufflevector(wz, wz, 0, 1), accz, false);
        accz = __builtin_amdgcn_fdot2(__builtin_shufflevector(hz, hz, 2, 3),
                                      __builtin_shufflevector(wz, wz, 2, 3), accz, false);
        accz = __builtin_amdgcn_fdot2(__builtin_shufflevector(hz, hz, 4, 5),
                                      __builtin_shufflevector(wz, wz, 4, 5), accz, false);
        accz = __builtin_amdgcn_fdot2(__builtin_shufflevector(hz, hz, 6, 7),
                                      __builtin_shufflevector(wz, wz, 6, 7), accz, false);
#else
        accz = fmaf((float)hz[0], (float)wz[0], accz);
        accz = fmaf((float)hz[1], (float)wz[1], accz);
        accz = fmaf((float)hz[2], (float)wz[2], accz);
        accz = fmaf((float)hz[3], (float)wz[3], accz);
        accz = fmaf((float)hz[4], (float)wz[4], accz);
        accz = fmaf((float)hz[5], (float)wz[5], accz);
        accz = fmaf((float)hz[6], (float)wz[6], accz);
        accz = fmaf((float)hz[7], (float)wz[7], accz);
#endif
    }
    accz += __shfl_xor(accz, 32);
    float za = accz * a_s2[c];
    float zd = accz * a_d2[c];
#pragma unroll
    for (int mq = 1; mq < 32; mq <<= 1) {
        za += __shfl_xor(za, mq);
        zd += __shfl_xor(zd, mq);
    }
    if (l < 32) z[(size_t)n * 32 + c] = (_Float16)accz;
    if (l == 0) {
        as2[n] = za * LOG2E;   // pre-scaled for exp2
        ad2[n] = zd * LOG2E;
    }
}

// ---------------- gather2 (fused softmax): out = (sum_j p_j * z[src_j]) / sum_j p_j + b2 ------
// R2-verified 2-deep software pipeline (best measured form).

__global__ void k_gather2(const _Float16* __restrict__ z, const float* __restrict__ as2,
                          const float* __restrict__ ad2, const int* __restrict__ cursor,
                          const int* __restrict__ col, const float* __restrict__ b2,
                          float* __restrict__ out, int N) {
    int n = blockIdx.x * 4 + (threadIdx.x >> 6);
    if (n >= N) return;
    int l = threadIdx.x & 63;
    int eo = l >> 3;
    int cg = l & 7;
    int beg = n * CAP;
    int deg = __builtin_amdgcn_readfirstlane(cursor[n]);
    if (deg > CAP) deg = CAP;
    int colv = 0;
    if (l < deg) colv = col[beg + l];
    float adn = ad2[n];
    f32x4 acc = {};
    float s = 0.f;

    const int nst = (deg + 7) >> 3;   // >=1
    int srcA = __shfl(colv, eo);
    float aA = as2[srcA];
    half4v zA = *((const half4v*)(z + (size_t)srcA * 32) + cg);
    for (int t = 0; t < nst; ++t) {
        int srcB = 0; float aB = 0.f; half4v zB = {};
        if (t + 1 < nst) {
            srcB = __shfl(colv, (t + 1) * 8 + eo);
            aB = as2[srcB];
            zB = *((const half4v*)(z + (size_t)srcB * 32) + cg);
        }
        float e = aA + adn;
        e = fmaxf(e, NEG_SLOPE * e);
        float p = (t * 8 + eo < deg) ? fast_exp2(e) : 0.f;
        s += p;
        acc += __builtin_convertvector(zA, f32x4) * p;
        srcA = srcB; aA = aB; zA = zB;
    }
    float ax = acc[0], ay = acc[1], az = acc[2], aw = acc[3];
#pragma unroll
    for (int mq = 8; mq < 64; mq <<= 1) {
        ax += __shfl_xor(ax, mq);
        ay += __shfl_xor(ay, mq);
        az += __shfl_xor(az, mq);
        aw += __shfl_xor(aw, mq);
        s += __shfl_xor(s, mq);
    }
    if (eo == 0) {
        float iv = 1.f / (s + 1e-16f);
        float4 bb = *(const float4*)(b2 + cg * 4);
        float4 v;
        v.x = ax * iv + bb.x;
        v.y = ay * iv + bb.y;
        v.z = az * iv + bb.z;
        v.w = aw * iv + bb.w;
        *(float4*)(out + (size_t)n * 32 + cg * 4) = v;
    }
}

// ---------------- launch ----------------

extern "C" void kernel_launch(void* const* d_in, const int* in_sizes, int n_in,
                              void* d_out, int out_size, void* d_ws, size_t ws_size,
                              hipStream_t stream) {
    const float* x    = (const float*)d_in[0];
    const int*   ei   = (const int*)d_in[1];
    const float* W1   = (const float*)d_in[2];
    const float* a_s1 = (const float*)d_in[3];
    const float* a_d1 = (const float*)d_in[4];
    const float* b1   = (const float*)d_in[5];
    const float* W2   = (const float*)d_in[6];
    const float* a_s2 = (const float*)d_in[7];
    const float* a_d2 = (const float*)d_in[8];
    const float* b2   = (const float*)d_in[9];
    float* out = (float*)d_out;

    const int N = in_sizes[0] / 256;
    const int E = in_sizes[1] / 2;
    const int* srcIdx = ei;
    const int* dstIdx = ei + E;

    char* ws = (char*)d_ws;
    size_t off = 0;
    auto alloc = [&](size_t bytes) {
        void* p = ws + off;
        off += (bytes + 255) & ~(size_t)255;
        return p;
    };
    _Float16* h1   = (_Float16*)alloc((size_t)N * 256 * 2);  // fp16 gather table (layer1)
    _Float16* z    = (_Float16*)alloc((size_t)N * 32 * 2);   // fp16 gather table (layer2)
    float* as1    = (float*)alloc((size_t)N * 16);
    float* ad1    = (float*)alloc((size_t)N * 16);
    float* as2    = (float*)alloc((size_t)N * 4);
    float* ad2    = (float*)alloc((size_t)N * 4);
    short* Wt     = (short*)alloc((size_t)256 * 256 * 2);    // W1^T bf16
    _Float16* W2t = (_Float16*)alloc((size_t)32 * 256 * 2);  // W2^T fp16
    int*   cursor = (int*)alloc((size_t)N * 4);
    int*   col    = (int*)alloc((size_t)N * CAP * 4);        // fixed-capacity buckets

    // prep (weights + bucket init)
    k_prepw<<<256, 256, 0, stream>>>(W1, Wt, W2, W2t, cursor, col, N);

    // fused layer-1 GEMM (BM=32) + edge scatter (k-loop-paced atomics, whole grid co-resident)
    const int nGemm = (N + 31) / 32;
    k_gemm1_scatter<<<nGemm, 256, 0, stream>>>(x, Wt, a_s1, a_d1, h1, as1, ad1, N,
                                               srcIdx, dstIdx, cursor, col, E);

    // fused: gather1-softmax + ELU + GEMM2 + alpha2
    k_fuse1<<<(N + 3) / 4, 256, 0, stream>>>(h1, as1, ad1, cursor, col, b1, W2t,
                                             a_s2, a_d2, z, as2, ad2, N);

    // layer 2 gather
    k_gather2<<<(N + 3) / 4, 256, 0, stream>>>(z, as2, ad2, cursor, col, b2, out, N);
}

// Round 15
// 248.737 us; speedup vs baseline: 1.0253x; 1.0253x over previous
//
#include <hip/hip_runtime.h>

#define NEG_SLOPE 0.2f
#define CAP 64  // per-node edge bucket capacity (Poisson(16)+selfloop; P(overflow)~1e-19)
#define LOG2E 1.44269504f

typedef short bf16x4 __attribute__((ext_vector_type(4)));
typedef short bf16x8 __attribute__((ext_vector_type(8)));
typedef float f32x4 __attribute__((ext_vector_type(4)));
typedef _Float16 half4v __attribute__((ext_vector_type(4)));
typedef _Float16 half8v __attribute__((ext_vector_type(8)));

// fp32 -> bf16 round-to-nearest-even
__device__ inline short bf16_rne(float x) {
    unsigned u = __float_as_uint(x);
    unsigned r = u + 0x7FFFu + ((u >> 16) & 1u);
    return (short)(r >> 16);
}

__device__ inline float fast_exp2(float x) {
#if __has_builtin(__builtin_amdgcn_exp2f)
    return __builtin_amdgcn_exp2f(x);
#else
    return exp2f(x);
#endif
}

// ---------------- prep: W1^T bf16, W2^T fp16, bucket init (cursor=1, self-loop slot 0) -------
// Coalesced-read transpose (R10 form).

__global__ void k_prepw(const float* __restrict__ W1, short* __restrict__ Wt,
                        const float* __restrict__ W2, _Float16* __restrict__ W2t,
                        int* __restrict__ cursor, int* __restrict__ col, int N) {
    int r = blockIdx.x;          // 0..255 (row of W1)
    int t = threadIdx.x;         // 0..255 (col of W1)
    Wt[(size_t)t * 256 + r] = bf16_rne(W1[(size_t)r * 256 + t]);
    if (t < 32) W2t[(size_t)t * 256 + r] = (_Float16)W2[(size_t)r * 32 + t];
    int gid = blockIdx.x * 256 + threadIdx.x;
    if (gid < N) {
        cursor[gid] = 1;                 // self-loop pre-counted
        col[(size_t)gid * CAP] = gid;    // self-loop in slot 0
    }
}

// ---------------- fused GEMM1 + scatter: BM=64, 8 waves, k-loop-paced atomics (R15) ----------
// Ledger: R12 (BM=64, 4 waves) = 72.6us @ 24% occ (grid-limited, 12 waves/CU);
// R14 (BM=32, 2x blocks) = 87.8us (2x per-block fixed costs + 2x B-stage traffic killed it).
// R15 keeps R12's tile/grid/LDS and doubles waves/block instead: 512 thr = 8 waves,
// wave w owns (row-half w>>2, head w&3) -> acc[2][4], complete alpha dots per wave
// (no cross-wave reduce). 24 waves/CU = 2x latency hiding for atomics + stage loads,
// with B-traffic, barrier count, and MFMA total unchanged. Scatter = 2 edges/thread,
// paced at kk={0:atomic e0, 1:store e0, 4:atomic e1, 5:store e1} (R12-proven).

__global__ __launch_bounds__(512) void k_gemm1_scatter(
        const float* __restrict__ x, const short* __restrict__ Wt,
        const float* __restrict__ a_src, const float* __restrict__ a_dst,
        _Float16* __restrict__ h1, float* __restrict__ as1, float* __restrict__ ad1, int N,
        const int* __restrict__ srcI, const int* __restrict__ dstI,
        int* __restrict__ cursor, int* __restrict__ col, int E) {
    __shared__ short Ab[64 * 40];   // [m][k], stride 40
    __shared__ short Bb[256 * 40];  // [n][k], stride 40
    const int tid = threadIdx.x;
    const int b = blockIdx.x;
    const int nGemm = gridDim.x;

    // ---- scatter slice: load 2 edges/thread now (plain loads, no atomics) ----
    const int chunk = (E + nGemm - 1) / nGemm;      // 1024 for E=800k, 782 blocks
    const int ss = b * chunk;
    const int se = (ss + chunk < E) ? (ss + chunk) : E;
    const int jb = ss + tid * 2;
    int2 d2 = make_int2(0, 0), s2 = make_int2(0, 0);
    int p0 = CAP, p1 = CAP;
    const bool pair = (jb + 1 < se);
    if (pair) {
        d2 = *(const int2*)(dstI + jb);
        s2 = *(const int2*)(srcI + jb);
    } else if (jb < se) {
        // ragged tail: scalar, immediate
        for (int i = jb; i < se; ++i) {
            int d = dstI[i];
            int p = atomicAdd(&cursor[d], 1);
            if (p < CAP) col[(size_t)d * CAP + p] = srcI[i];
        }
    }

    // ---- GEMM tile (BM=64, 8 waves) with paced scatter ops ----
    const int lane = tid & 63;
    const int w = tid >> 6;              // wave 0..7
    const int head = w & 3;              // head of this wave
    const int rw = w >> 2;               // row-half (0: rows 0-31, 1: rows 32-63)
    const int row0 = b * 64;
    const int m15 = lane & 15, quad4 = lane >> 4;

    f32x4 acc[2][4] = {};

    const int arow = tid >> 3;           // 0..63
    const int akseg = (tid & 7) * 4;     // 0,4,...,28

#pragma unroll
    for (int kk = 0; kk < 8; ++kk) {
        const int k0 = kk * 32;
        {   // A-stage: 512 threads cover 64 rows x 8 k-segs of 4
            int row = row0 + arow;
            float vals[4];
            if (row < N) {
                float4 v0 = *(const float4*)(x + (size_t)row * 256 + k0 + akseg);
                vals[0] = v0.x; vals[1] = v0.y; vals[2] = v0.z; vals[3] = v0.w;
            } else {
#pragma unroll
                for (int i = 0; i < 4; ++i) vals[i] = 0.f;
            }
            short buf[4];
#pragma unroll
            for (int i = 0; i < 4; ++i) buf[i] = bf16_rne(vals[i]);
            *(bf16x4*)&Ab[arow * 40 + akseg] = *(bf16x4*)&buf[0];
        }
        {   // B-stage: 1024 bf16x8 slots (256 rows x 4 segs) / 512 threads = 2 each
#pragma unroll
            for (int sl = 0; sl < 2; ++sl) {
                int slot = tid + sl * 512;
                int brow = slot >> 2, seg = slot & 3;
                *(bf16x8*)&Bb[brow * 40 + seg * 8] =
                    *(const bf16x8*)(Wt + (size_t)brow * 256 + k0 + seg * 8);
            }
        }
        // paced scatter: atomic e0 @kk0, store e0 @kk1, atomic e1 @kk4, store e1 @kk5.
        if (pair) {
            if (kk == 0) {
                p0 = atomicAdd(&cursor[d2.x], 1);
            } else if (kk == 1) {
                if (p0 < CAP) col[(size_t)d2.x * CAP + p0] = s2.x;
            } else if (kk == 4) {
                p1 = atomicAdd(&cursor[d2.y], 1);
            } else if (kk == 5) {
                if (p1 < CAP) col[(size_t)d2.y * CAP + p1] = s2.y;
            }
        }
        __syncthreads();
        bf16x8 ab[2];
#pragma unroll
        for (int mt = 0; mt < 2; ++mt)
            ab[mt] = *(const bf16x8*)&Ab[(rw * 32 + mt * 16 + m15) * 40 + quad4 * 8];
#pragma unroll
        for (int nt = 0; nt < 4; ++nt) {
            int nn = head * 64 + nt * 16 + m15;
            bf16x8 bb = *(const bf16x8*)&Bb[nn * 40 + quad4 * 8];
#pragma unroll
            for (int mt = 0; mt < 2; ++mt)
                acc[mt][nt] = __builtin_amdgcn_mfma_f32_16x16x32_bf16(ab[mt], bb, acc[mt][nt], 0, 0, 0);
        }
        __syncthreads();
    }
#pragma unroll
    for (int mt = 0; mt < 2; ++mt) {
        float va[4] = {0.f, 0.f, 0.f, 0.f};
        float vd[4] = {0.f, 0.f, 0.f, 0.f};
#pragma unroll
        for (int nt = 0; nt < 4; ++nt) {
            int colg = head * 64 + nt * 16 + m15;
            float asv = a_src[colg];
            float adv = a_dst[colg];
#pragma unroll
            for (int r = 0; r < 4; ++r) {
                float accv = acc[mt][nt][r];
                int row = row0 + rw * 32 + mt * 16 + quad4 * 4 + r;
                if (row < N) h1[(size_t)row * 256 + colg] = (_Float16)accv;
                va[r] = fmaf(accv, asv, va[r]);
                vd[r] = fmaf(accv, adv, vd[r]);
            }
        }
#pragma unroll
        for (int r = 0; r < 4; ++r) {
#pragma unroll
            for (int mq = 1; mq < 16; mq <<= 1) {
                va[r] += __shfl_xor(va[r], mq);
                vd[r] += __shfl_xor(vd[r], mq);
            }
            int row = row0 + rw * 32 + mt * 16 + quad4 * 4 + r;
            if (m15 == 0 && row < N) {
                as1[(size_t)row * 4 + head] = va[r] * LOG2E;   // pre-scaled for exp2
                ad1[(size_t)row * 4 + head] = vd[r] * LOG2E;
            }
        }
    }
}

// ---------------- fused gather1 + GEMM2 + alpha2 (R1-verified inner loop, best measured:
// 69.9 us. Memory-bound on the h1 gather stream (R8: VALU cuts don't help) — keep simple). ----

__global__ __launch_bounds__(256) void k_fuse1(
        const _Float16* __restrict__ h1, const float* __restrict__ as1,
        const float* __restrict__ ad1, const int* __restrict__ cursor,
        const int* __restrict__ col, const float* __restrict__ b1,
        const _Float16* __restrict__ W2t, const float* __restrict__ a_s2,
        const float* __restrict__ a_d2, _Float16* __restrict__ z,
        float* __restrict__ as2, float* __restrict__ ad2, int N) {
    __shared__ _Float16 W2s[32 * 264];   // [c][k], pad 8 shorts (16B) per row
    __shared__ _Float16 h2s[4 * 256];    // per-wave h2 slot
    const int tid = threadIdx.x;
    const int l = tid & 63;
    const int wave = tid >> 6;
    const int n = blockIdx.x * 4 + wave;

    for (int i8 = tid; i8 < 1024; i8 += 256) {
        int elem = i8 * 8;
        int row = elem >> 8, k = elem & 255;
        *(half8v*)&W2s[row * 264 + k] = *(const half8v*)(W2t + (size_t)row * 256 + k);
    }
    __syncthreads();
    if (n >= N) return;

    const int head = l >> 4;
    const int beg = n * CAP;
    int deg = __builtin_amdgcn_readfirstlane(cursor[n]);
    if (deg > CAP) deg = CAP;
    // whole bucket in one coalesced load; per-edge index comes from readlane (register)
    int colv = 0;
    if (l < deg) colv = col[beg + l];
    float adv = ad1[(size_t)n * 4 + head];

    f32x4 a0 = {}, a1 = {}, a2 = {}, a3 = {};
    float s0 = 0.f, s1 = 0.f, s2 = 0.f, s3 = 0.f;
    int j = 0;
    for (; j + 3 < deg; j += 4) {
        int c0 = __builtin_amdgcn_readlane(colv, j);
        int c1 = __builtin_amdgcn_readlane(colv, j + 1);
        int c2 = __builtin_amdgcn_readlane(colv, j + 2);
        int c3 = __builtin_amdgcn_readlane(colv, j + 3);
        float e0 = as1[(size_t)c0 * 4 + head] + adv;
        float e1 = as1[(size_t)c1 * 4 + head] + adv;
        float e2 = as1[(size_t)c2 * 4 + head] + adv;
        float e3 = as1[(size_t)c3 * 4 + head] + adv;
        e0 = fmaxf(e0, NEG_SLOPE * e0); e1 = fmaxf(e1, NEG_SLOPE * e1);
        e2 = fmaxf(e2, NEG_SLOPE * e2); e3 = fmaxf(e3, NEG_SLOPE * e3);
        float p0 = fast_exp2(e0), p1 = fast_exp2(e1);
        float p2 = fast_exp2(e2), p3 = fast_exp2(e3);
        half4v h0 = *((const half4v*)(h1 + (size_t)c0 * 256) + l);
        half4v hv1 = *((const half4v*)(h1 + (size_t)c1 * 256) + l);
        half4v h2 = *((const half4v*)(h1 + (size_t)c2 * 256) + l);
        half4v h3 = *((const half4v*)(h1 + (size_t)c3 * 256) + l);
        s0 += p0; s1 += p1; s2 += p2; s3 += p3;
        a0 += __builtin_convertvector(h0, f32x4) * p0;
        a1 += __builtin_convertvector(hv1, f32x4) * p1;
        a2 += __builtin_convertvector(h2, f32x4) * p2;
        a3 += __builtin_convertvector(h3, f32x4) * p3;
    }
    for (; j < deg; ++j) {
        int c0 = __builtin_amdgcn_readlane(colv, j);
        float e0 = as1[(size_t)c0 * 4 + head] + adv;
        e0 = fmaxf(e0, NEG_SLOPE * e0);
        float p0 = fast_exp2(e0);
        half4v h0 = *((const half4v*)(h1 + (size_t)c0 * 256) + l);
        s0 += p0;
        a0 += __builtin_convertvector(h0, f32x4) * p0;
    }
    f32x4 at = (a0 + a1) + (a2 + a3);
    float iv = 1.f / ((s0 + s1) + (s2 + s3) + 1e-16f);
    float4 bb = *(const float4*)(b1 + l * 4);
    float4 v;
    v.x = at[0] * iv + bb.x;
    v.y = at[1] * iv + bb.y;
    v.z = at[2] * iv + bb.z;
    v.w = at[3] * iv + bb.w;
    v.x = (v.x > 0.f) ? v.x : (__expf(v.x) - 1.f);
    v.y = (v.y > 0.f) ? v.y : (__expf(v.y) - 1.f);
    v.z = (v.z > 0.f) ? v.z : (__expf(v.z) - 1.f);
    v.w = (v.w > 0.f) ? v.w : (__expf(v.w) - 1.f);
    half4v hv;
    hv.x = (_Float16)v.x; hv.y = (_Float16)v.y; hv.z = (_Float16)v.z; hv.w = (_Float16)v.w;
    *((half4v*)(h2s + wave * 256) + l) = hv;   // same-wave LDS, no barrier needed

    // GEMM2 row: lane l -> channel c = l&31, k-half kh = (l>>5)*128
    int c = l & 31;
    int kh = (l >> 5) * 128;
    const _Float16* hrow = h2s + wave * 256 + kh;
    const _Float16* wrow = W2s + c * 264 + kh;
    float accz = 0.f;
#pragma unroll
    for (int k = 0; k < 128; k += 8) {
        half8v hz = *(const half8v*)(hrow + k);
        half8v wz = *(const half8v*)(wrow + k);
#if __has_builtin(__builtin_amdgcn_fdot2)
        accz = __builtin_amdgcn_fdot2(__builtin_shufflevector(hz, hz, 0, 1),
                                      __builtin_shufflevector(wz, wz, 0, 1), accz, false);
        accz = __builtin_amdgcn_fdot2(__builtin_shufflevector(hz, hz, 2, 3),
                                      __builtin_shufflevector(wz, wz, 2, 3), accz, false);
        accz = __builtin_amdgcn_fdot2(__builtin_shufflevector(hz, hz, 4, 5),
                                      __builtin_shufflevector(wz, wz, 4, 5), accz, false);
        accz = __builtin_amdgcn_fdot2(__builtin_shufflevector(hz, hz, 6, 7),
                                      __builtin_shufflevector(wz, wz, 6, 7), accz, false);
#else
        accz = fmaf((float)hz[0], (float)wz[0], accz);
        accz = fmaf((float)hz[1], (float)wz[1], accz);
        accz = fmaf((float)hz[2], (float)wz[2], accz);
        accz = fmaf((float)hz[3], (float)wz[3], accz);
        accz = fmaf((float)hz[4], (float)wz[4], accz);
        accz = fmaf((float)hz[5], (float)wz[5], accz);
        accz = fmaf((float)hz[6], (float)wz[6], accz);
        accz = fmaf((float)hz[7], (float)wz[7], accz);
#endif
    }
    accz += __shfl_xor(accz, 32);
    float za = accz * a_s2[c];
    float zd = accz * a_d2[c];
#pragma unroll
    for (int mq = 1; mq < 32; mq <<= 1) {
        za += __shfl_xor(za, mq);
        zd += __shfl_xor(zd, mq);
    }
    if (l < 32) z[(size_t)n * 32 + c] = (_Float16)accz;
    if (l == 0) {
        as2[n] = za * LOG2E;   // pre-scaled for exp2
        ad2[n] = zd * LOG2E;
    }
}

// ---------------- gather2 (fused softmax): out = (sum_j p_j * z[src_j]) / sum_j p_j + b2 ------
// R2-verified 2-deep software pipeline (best measured form).

__global__ void k_gather2(const _Float16* __restrict__ z, const float* __restrict__ as2,
                          const float* __restrict__ ad2, const int* __restrict__ cursor,
                          const int* __restrict__ col, const float* __restrict__ b2,
                          float* __restrict__ out, int N) {
    int n = blockIdx.x * 4 + (threadIdx.x >> 6);
    if (n >= N) return;
    int l = threadIdx.x & 63;
    int eo = l >> 3;
    int cg = l & 7;
    int beg = n * CAP;
    int deg = __builtin_amdgcn_readfirstlane(cursor[n]);
    if (deg > CAP) deg = CAP;
    int colv = 0;
    if (l < deg) colv = col[beg + l];
    float adn = ad2[n];
    f32x4 acc = {};
    float s = 0.f;

    const int nst = (deg + 7) >> 3;   // >=1
    int srcA = __shfl(colv, eo);
    float aA = as2[srcA];
    half4v zA = *((const half4v*)(z + (size_t)srcA * 32) + cg);
    for (int t = 0; t < nst; ++t) {
        int srcB = 0; float aB = 0.f; half4v zB = {};
        if (t + 1 < nst) {
            srcB = __shfl(colv, (t + 1) * 8 + eo);
            aB = as2[srcB];
            zB = *((const half4v*)(z + (size_t)srcB * 32) + cg);
        }
        float e = aA + adn;
        e = fmaxf(e, NEG_SLOPE * e);
        float p = (t * 8 + eo < deg) ? fast_exp2(e) : 0.f;
        s += p;
        acc += __builtin_convertvector(zA, f32x4) * p;
        srcA = srcB; aA = aB; zA = zB;
    }
    float ax = acc[0], ay = acc[1], az = acc[2], aw = acc[3];
#pragma unroll
    for (int mq = 8; mq < 64; mq <<= 1) {
        ax += __shfl_xor(ax, mq);
        ay += __shfl_xor(ay, mq);
        az += __shfl_xor(az, mq);
        aw += __shfl_xor(aw, mq);
        s += __shfl_xor(s, mq);
    }
    if (eo == 0) {
        float iv = 1.f / (s + 1e-16f);
        float4 bb = *(const float4*)(b2 + cg * 4);
        float4 v;
        v.x = ax * iv + bb.x;
        v.y = ay * iv + bb.y;
        v.z = az * iv + bb.z;
        v.w = aw * iv + bb.w;
        *(float4*)(out + (size_t)n * 32 + cg * 4) = v;
    }
}

// ---------------- launch ----------------

extern "C" void kernel_launch(void* const* d_in, const int* in_sizes, int n_in,
                              void* d_out, int out_size, void* d_ws, size_t ws_size,
                              hipStream_t stream) {
    const float* x    = (const float*)d_in[0];
    const int*   ei   = (const int*)d_in[1];
    const float* W1   = (const float*)d_in[2];
    const float* a_s1 = (const float*)d_in[3];
    const float* a_d1 = (const float*)d_in[4];
    const float* b1   = (const float*)d_in[5];
    const float* W2   = (const float*)d_in[6];
    const float* a_s2 = (const float*)d_in[7];
    const float* a_d2 = (const float*)d_in[8];
    const float* b2   = (const float*)d_in[9];
    float* out = (float*)d_out;

    const int N = in_sizes[0] / 256;
    const int E = in_sizes[1] / 2;
    const int* srcIdx = ei;
    const int* dstIdx = ei + E;

    char* ws = (char*)d_ws;
    size_t off = 0;
    auto alloc = [&](size_t bytes) {
        void* p = ws + off;
        off += (bytes + 255) & ~(size_t)255;
        return p;
    };
    _Float16* h1   = (_Float16*)alloc((size_t)N * 256 * 2);  // fp16 gather table (layer1)
    _Float16* z    = (_Float16*)alloc((size_t)N * 32 * 2);   // fp16 gather table (layer2)
    float* as1    = (float*)alloc((size_t)N * 16);
    float* ad1    = (float*)alloc((size_t)N * 16);
    float* as2    = (float*)alloc((size_t)N * 4);
    float* ad2    = (float*)alloc((size_t)N * 4);
    short* Wt     = (short*)alloc((size_t)256 * 256 * 2);    // W1^T bf16
    _Float16* W2t = (_Float16*)alloc((size_t)32 * 256 * 2);  // W2^T fp16
    int*   cursor = (int*)alloc((size_t)N * 4);
    int*   col    = (int*)alloc((size_t)N * CAP * 4);        // fixed-capacity buckets

    // prep (weights + bucket init)
    k_prepw<<<256, 256, 0, stream>>>(W1, Wt, W2, W2t, cursor, col, N);

    // fused layer-1 GEMM (BM=64, 8 waves) + edge scatter (k-loop-paced atomics)
    const int nGemm = (N + 63) / 64;
    k_gemm1_scatter<<<nGemm, 512, 0, stream>>>(x, Wt, a_s1, a_d1, h1, as1, ad1, N,
                                               srcIdx, dstIdx, cursor, col, E);

    // fused: gather1-softmax + ELU + GEMM2 + alpha2
    k_fuse1<<<(N + 3) / 4, 256, 0, stream>>>(h1, as1, ad1, cursor, col, b1, W2t,
                                             a_s2, a_d2, z, as2, ad2, N);

    // layer 2 gather
    k_gather2<<<(N + 3) / 4, 256, 0, stream>>>(z, as2, ad2, cursor, col, b2, out, N);
}

// Round 16
// 245.245 us; speedup vs baseline: 1.0399x; 1.0142x over previous
//
#include <hip/hip_runtime.h>

#define NEG_SLOPE 0.2f
#define CAP 64  // per-node edge bucket capacity (Poisson(16)+selfloop; P(overflow)~1e-19)
#define LOG2E 1.44269504f

typedef short bf16x8 __attribute__((ext_vector_type(8)));
typedef float f32x4 __attribute__((ext_vector_type(4)));
typedef _Float16 half4v __attribute__((ext_vector_type(4)));
typedef _Float16 half8v __attribute__((ext_vector_type(8)));

// fp32 -> bf16 round-to-nearest-even
__device__ inline short bf16_rne(float x) {
    unsigned u = __float_as_uint(x);
    unsigned r = u + 0x7FFFu + ((u >> 16) & 1u);
    return (short)(r >> 16);
}

__device__ inline float fast_exp2(float x) {
#if __has_builtin(__builtin_amdgcn_exp2f)
    return __builtin_amdgcn_exp2f(x);
#else
    return exp2f(x);
#endif
}

// ---------------- prep: W1^T bf16, W2^T fp16, bucket init (cursor=1, self-loop slot 0) -------
// Coalesced-read transpose (R10 form).

__global__ void k_prepw(const float* __restrict__ W1, short* __restrict__ Wt,
                        const float* __restrict__ W2, _Float16* __restrict__ W2t,
                        int* __restrict__ cursor, int* __restrict__ col, int N) {
    int r = blockIdx.x;          // 0..255 (row of W1)
    int t = threadIdx.x;         // 0..255 (col of W1)
    Wt[(size_t)t * 256 + r] = bf16_rne(W1[(size_t)r * 256 + t]);
    if (t < 32) W2t[(size_t)t * 256 + r] = (_Float16)W2[(size_t)r * 32 + t];
    int gid = blockIdx.x * 256 + threadIdx.x;
    if (gid < N) {
        cursor[gid] = 1;                 // self-loop pre-counted
        col[(size_t)gid * CAP] = gid;    // self-loop in slot 0
    }
}

// ---------------- fused GEMM1 + scatter: k-loop-paced atomics (R12-verified best: 72.6us) ----
// Pacing ledger: burst=98 (R11), coarse-parity=80 (R9), fine k-loop-paced=72.6 (R12).
// Concurrency ledger: BM=32 (R14, 87.8) and 8-wave (R15, 74.5) both WORSE -> scatter is at
// the device atomic-throughput floor (~5-6 RMW/cy device-wide); this geometry is final.

__global__ __launch_bounds__(256) void k_gemm1_scatter(
        const float* __restrict__ x, const short* __restrict__ Wt,
        const float* __restrict__ a_src, const float* __restrict__ a_dst,
        _Float16* __restrict__ h1, float* __restrict__ as1, float* __restrict__ ad1, int N,
        const int* __restrict__ srcI, const int* __restrict__ dstI,
        int* __restrict__ cursor, int* __restrict__ col, int E) {
    __shared__ short Ab[64 * 40];   // [m][k], stride 40
    __shared__ short Bb[256 * 40];  // [n][k], stride 40
    const int tid = threadIdx.x;
    const int b = blockIdx.x;
    const int nGemm = gridDim.x;

    // ---- scatter slice: load 4 edges/thread now (plain loads, no atomics) ----
    const int chunk = (E + nGemm - 1) / nGemm;
    const int ss = b * chunk;
    const int se = (ss + chunk < E) ? (ss + chunk) : E;
    const int jb = ss + tid * 4;
    int4 d4 = make_int4(0, 0, 0, 0), s4 = make_int4(0, 0, 0, 0);
    int p0 = CAP, p1 = CAP, p2 = CAP, p3 = CAP;
    const bool quad = (jb + 3 < se);
    if (quad) {
        d4 = *(const int4*)(dstI + jb);
        s4 = *(const int4*)(srcI + jb);
    } else if (jb < se) {
        // ragged tail (not hit for E=800k): scalar, immediate
        for (int i = jb; i < se; ++i) {
            int d = dstI[i];
            int p = atomicAdd(&cursor[d], 1);
            if (p < CAP) col[(size_t)d * CAP + p] = srcI[i];
        }
    }

    // ---- GEMM tile with paced scatter ops ----
    const int lane = tid & 63;
    const int wc = tid >> 6;             // wave index == head
    const int row0 = b * 64;
    const int m15 = lane & 15, quad4 = lane >> 4;

    f32x4 acc[4][4] = {};

    const int arow = tid >> 2;           // 0..63
    const int akseg = (tid & 3) * 8;     // 0,8,16,24

#pragma unroll
    for (int kk = 0; kk < 8; ++kk) {
        const int k0 = kk * 32;
        {
            int row = row0 + arow;
            float vals[8];
            if (row < N) {
                float4 v0 = *(const float4*)(x + (size_t)row * 256 + k0 + akseg);
                float4 v1 = *(const float4*)(x + (size_t)row * 256 + k0 + akseg + 4);
                vals[0] = v0.x; vals[1] = v0.y; vals[2] = v0.z; vals[3] = v0.w;
                vals[4] = v1.x; vals[5] = v1.y; vals[6] = v1.z; vals[7] = v1.w;
            } else {
#pragma unroll
                for (int i = 0; i < 8; ++i) vals[i] = 0.f;
            }
            short buf[8];
#pragma unroll
            for (int i = 0; i < 8; ++i) buf[i] = bf16_rne(vals[i]);
            *(bf16x8*)&Ab[arow * 40 + akseg] = *(bf16x8*)&buf[0];
        }
        {
#pragma unroll
            for (int s = 0; s < 4; ++s)
                *(bf16x8*)&Bb[tid * 40 + s * 8] =
                    *(const bf16x8*)(Wt + (size_t)tid * 256 + k0 + s * 8);
        }
        // paced scatter: even iter -> issue atomic for edge kk/2; odd -> store edge kk/2.
        if (quad) {
            const int e = kk >> 1;
            const int d = (e == 0) ? d4.x : (e == 1) ? d4.y : (e == 2) ? d4.z : d4.w;
            if ((kk & 1) == 0) {
                int pr = atomicAdd(&cursor[d], 1);
                if (e == 0) p0 = pr; else if (e == 1) p1 = pr;
                else if (e == 2) p2 = pr; else p3 = pr;
            } else {
                const int s = (e == 0) ? s4.x : (e == 1) ? s4.y : (e == 2) ? s4.z : s4.w;
                const int pr = (e == 0) ? p0 : (e == 1) ? p1 : (e == 2) ? p2 : p3;
                if (pr < CAP) col[(size_t)d * CAP + pr] = s;
            }
        }
        __syncthreads();
        bf16x8 ab[4];
#pragma unroll
        for (int mt = 0; mt < 4; ++mt)
            ab[mt] = *(const bf16x8*)&Ab[(mt * 16 + m15) * 40 + quad4 * 8];
#pragma unroll
        for (int nt = 0; nt < 4; ++nt) {
            int nn = wc * 64 + nt * 16 + m15;
            bf16x8 bb = *(const bf16x8*)&Bb[nn * 40 + quad4 * 8];
#pragma unroll
            for (int mt = 0; mt < 4; ++mt)
                acc[mt][nt] = __builtin_amdgcn_mfma_f32_16x16x32_bf16(ab[mt], bb, acc[mt][nt], 0, 0, 0);
        }
        __syncthreads();
    }
    const int head = wc;
#pragma unroll
    for (int mt = 0; mt < 4; ++mt) {
        float va[4] = {0.f, 0.f, 0.f, 0.f};
        float vd[4] = {0.f, 0.f, 0.f, 0.f};
#pragma unroll
        for (int nt = 0; nt < 4; ++nt) {
            int colg = wc * 64 + nt * 16 + m15;
            float asv = a_src[colg];
            float adv = a_dst[colg];
#pragma unroll
            for (int r = 0; r < 4; ++r) {
                float accv = acc[mt][nt][r];
                int row = row0 + mt * 16 + quad4 * 4 + r;
                if (row < N) h1[(size_t)row * 256 + colg] = (_Float16)accv;
                va[r] = fmaf(accv, asv, va[r]);
                vd[r] = fmaf(accv, adv, vd[r]);
            }
        }
#pragma unroll
        for (int r = 0; r < 4; ++r) {
#pragma unroll
            for (int mq = 1; mq < 16; mq <<= 1) {
                va[r] += __shfl_xor(va[r], mq);
                vd[r] += __shfl_xor(vd[r], mq);
            }
            int row = row0 + mt * 16 + quad4 * 4 + r;
            if (m15 == 0 && row < N) {
                as1[(size_t)row * 4 + head] = va[r] * LOG2E;   // pre-scaled for exp2
                ad1[(size_t)row * 4 + head] = vd[r] * LOG2E;
            }
        }
    }
}

// ---------------- fused gather1 + GEMM2 + alpha2 (R1-verified inner loop, best measured:
// 69.9 us. Memory-bound on the h1 gather stream (R8: VALU cuts don't help) — keep simple). ----

__global__ __launch_bounds__(256) void k_fuse1(
        const _Float16* __restrict__ h1, const float* __restrict__ as1,
        const float* __restrict__ ad1, const int* __restrict__ cursor,
        const int* __restrict__ col, const float* __restrict__ b1,
        const _Float16* __restrict__ W2t, const float* __restrict__ a_s2,
        const float* __restrict__ a_d2, _Float16* __restrict__ z,
        float* __restrict__ as2, float* __restrict__ ad2, int N) {
    __shared__ _Float16 W2s[32 * 264];   // [c][k], pad 8 shorts (16B) per row
    __shared__ _Float16 h2s[4 * 256];    // per-wave h2 slot
    const int tid = threadIdx.x;
    const int l = tid & 63;
    const int wave = tid >> 6;
    const int n = blockIdx.x * 4 + wave;

    for (int i8 = tid; i8 < 1024; i8 += 256) {
        int elem = i8 * 8;
        int row = elem >> 8, k = elem & 255;
        *(half8v*)&W2s[row * 264 + k] = *(const half8v*)(W2t + (size_t)row * 256 + k);
    }
    __syncthreads();
    if (n >= N) return;

    const int head = l >> 4;
    const int beg = n * CAP;
    int deg = __builtin_amdgcn_readfirstlane(cursor[n]);
    if (deg > CAP) deg = CAP;
    // whole bucket in one coalesced load; per-edge index comes from readlane (register)
    int colv = 0;
    if (l < deg) colv = col[beg + l];
    float adv = ad1[(size_t)n * 4 + head];

    f32x4 a0 = {}, a1 = {}, a2 = {}, a3 = {};
    float s0 = 0.f, s1 = 0.f, s2 = 0.f, s3 = 0.f;
    int j = 0;
    for (; j + 3 < deg; j += 4) {
        int c0 = __builtin_amdgcn_readlane(colv, j);
        int c1 = __builtin_amdgcn_readlane(colv, j + 1);
        int c2 = __builtin_amdgcn_readlane(colv, j + 2);
        int c3 = __builtin_amdgcn_readlane(colv, j + 3);
        float e0 = as1[(size_t)c0 * 4 + head] + adv;
        float e1 = as1[(size_t)c1 * 4 + head] + adv;
        float e2 = as1[(size_t)c2 * 4 + head] + adv;
        float e3 = as1[(size_t)c3 * 4 + head] + adv;
        e0 = fmaxf(e0, NEG_SLOPE * e0); e1 = fmaxf(e1, NEG_SLOPE * e1);
        e2 = fmaxf(e2, NEG_SLOPE * e2); e3 = fmaxf(e3, NEG_SLOPE * e3);
        float p0 = fast_exp2(e0), p1 = fast_exp2(e1);
        float p2 = fast_exp2(e2), p3 = fast_exp2(e3);
        half4v h0 = *((const half4v*)(h1 + (size_t)c0 * 256) + l);
        half4v hv1 = *((const half4v*)(h1 + (size_t)c1 * 256) + l);
        half4v h2 = *((const half4v*)(h1 + (size_t)c2 * 256) + l);
        half4v h3 = *((const half4v*)(h1 + (size_t)c3 * 256) + l);
        s0 += p0; s1 += p1; s2 += p2; s3 += p3;
        a0 += __builtin_convertvector(h0, f32x4) * p0;
        a1 += __builtin_convertvector(hv1, f32x4) * p1;
        a2 += __builtin_convertvector(h2, f32x4) * p2;
        a3 += __builtin_convertvector(h3, f32x4) * p3;
    }
    for (; j < deg; ++j) {
        int c0 = __builtin_amdgcn_readlane(colv, j);
        float e0 = as1[(size_t)c0 * 4 + head] + adv;
        e0 = fmaxf(e0, NEG_SLOPE * e0);
        float p0 = fast_exp2(e0);
        half4v h0 = *((const half4v*)(h1 + (size_t)c0 * 256) + l);
        s0 += p0;
        a0 += __builtin_convertvector(h0, f32x4) * p0;
    }
    f32x4 at = (a0 + a1) + (a2 + a3);
    float iv = 1.f / ((s0 + s1) + (s2 + s3) + 1e-16f);
    float4 bb = *(const float4*)(b1 + l * 4);
    float4 v;
    v.x = at[0] * iv + bb.x;
    v.y = at[1] * iv + bb.y;
    v.z = at[2] * iv + bb.z;
    v.w = at[3] * iv + bb.w;
    v.x = (v.x > 0.f) ? v.x : (__expf(v.x) - 1.f);
    v.y = (v.y > 0.f) ? v.y : (__expf(v.y) - 1.f);
    v.z = (v.z > 0.f) ? v.z : (__expf(v.z) - 1.f);
    v.w = (v.w > 0.f) ? v.w : (__expf(v.w) - 1.f);
    half4v hv;
    hv.x = (_Float16)v.x; hv.y = (_Float16)v.y; hv.z = (_Float16)v.z; hv.w = (_Float16)v.w;
    *((half4v*)(h2s + wave * 256) + l) = hv;   // same-wave LDS, no barrier needed

    // GEMM2 row: lane l -> channel c = l&31, k-half kh = (l>>5)*128
    int c = l & 31;
    int kh = (l >> 5) * 128;
    const _Float16* hrow = h2s + wave * 256 + kh;
    const _Float16* wrow = W2s + c * 264 + kh;
    float accz = 0.f;
#pragma unroll
    for (int k = 0; k < 128; k += 8) {
        half8v hz = *(const half8v*)(hrow + k);
        half8v wz = *(const half8v*)(wrow + k);
#if __has_builtin(__builtin_amdgcn_fdot2)
        accz = __builtin_amdgcn_fdot2(__builtin_shufflevector(hz, hz, 0, 1),
                                      __builtin_shufflevector(wz, wz, 0, 1), accz, false);
        accz = __builtin_amdgcn_fdot2(__builtin_shufflevector(hz, hz, 2, 3),
                                      __builtin_shufflevector(wz, wz, 2, 3), accz, false);
        accz = __builtin_amdgcn_fdot2(__builtin_shufflevector(hz, hz, 4, 5),
                                      __builtin_shufflevector(wz, wz, 4, 5), accz, false);
        accz = __builtin_amdgcn_fdot2(__builtin_shufflevector(hz, hz, 6, 7),
                                      __builtin_shufflevector(wz, wz, 6, 7), accz, false);
#else
        accz = fmaf((float)hz[0], (float)wz[0], accz);
        accz = fmaf((float)hz[1], (float)wz[1], accz);
        accz = fmaf((float)hz[2], (float)wz[2], accz);
        accz = fmaf((float)hz[3], (float)wz[3], accz);
        accz = fmaf((float)hz[4], (float)wz[4], accz);
        accz = fmaf((float)hz[5], (float)wz[5], accz);
        accz = fmaf((float)hz[6], (float)wz[6], accz);
        accz = fmaf((float)hz[7], (float)wz[7], accz);
#endif
    }
    accz += __shfl_xor(accz, 32);
    float za = accz * a_s2[c];
    float zd = accz * a_d2[c];
#pragma unroll
    for (int mq = 1; mq < 32; mq <<= 1) {
        za += __shfl_xor(za, mq);
        zd += __shfl_xor(zd, mq);
    }
    if (l < 32) z[(size_t)n * 32 + c] = (_Float16)accz;
    if (l == 0) {
        as2[n] = za * LOG2E;   // pre-scaled for exp2
        ad2[n] = zd * LOG2E;
    }
}

// ---------------- gather2: BURST-MLP rewrite (R16) -------------------------------------------
// Old form carried srcA/zA serially across the t-loop -> ~(nst+1) dependent memory rounds
// per node-wave. New form: colv (one coalesced load) -> all shfls -> ALL <=8 iterations'
// as2+z loads issued back-to-back (wave-uniform t<nst guards, no extra traffic; static
// register indices via full unroll) -> consume. Critical path = 2 memory rounds.

__global__ void k_gather2(const _Float16* __restrict__ z, const float* __restrict__ as2,
                          const float* __restrict__ ad2, const int* __restrict__ cursor,
                          const int* __restrict__ col, const float* __restrict__ b2,
                          float* __restrict__ out, int N) {
    int n = blockIdx.x * 4 + (threadIdx.x >> 6);
    if (n >= N) return;
    int l = threadIdx.x & 63;
    int eo = l >> 3;
    int cg = l & 7;
    int beg = n * CAP;
    int deg = __builtin_amdgcn_readfirstlane(cursor[n]);
    if (deg > CAP) deg = CAP;
    int colv = 0;
    if (l < deg) colv = col[beg + l];
    float adn = ad2[n];

    const int nst = (deg + 7) >> 3;   // 1..8 (deg>=1 via self-loop)

    float av_[8];
    half4v zv_[8];
#pragma unroll
    for (int t = 0; t < 8; ++t) {
        if (t < nst) {
            int idx = t * 8 + eo;
            int sidx = (idx < deg) ? idx : 0;    // lane-0 colv is always valid (deg>=1)
            int src = __shfl(colv, sidx);
            av_[t] = as2[src];
            zv_[t] = *((const half4v*)(z + (size_t)src * 32) + cg);
        }
    }

    f32x4 acc = {};
    float s = 0.f;
#pragma unroll
    for (int t = 0; t < 8; ++t) {
        if (t < nst) {
            int idx = t * 8 + eo;
            float e = av_[t] + adn;
            e = fmaxf(e, NEG_SLOPE * e);
            float p = (idx < deg) ? fast_exp2(e) : 0.f;
            s += p;
            acc += __builtin_convertvector(zv_[t], f32x4) * p;
        }
    }

    float ax = acc[0], ay = acc[1], az = acc[2], aw = acc[3];
#pragma unroll
    for (int mq = 8; mq < 64; mq <<= 1) {
        ax += __shfl_xor(ax, mq);
        ay += __shfl_xor(ay, mq);
        az += __shfl_xor(az, mq);
        aw += __shfl_xor(aw, mq);
        s += __shfl_xor(s, mq);
    }
    if (eo == 0) {
        float iv = 1.f / (s + 1e-16f);
        float4 bb = *(const float4*)(b2 + cg * 4);
        float4 v;
        v.x = ax * iv + bb.x;
        v.y = ay * iv + bb.y;
        v.z = az * iv + bb.z;
        v.w = aw * iv + bb.w;
        *(float4*)(out + (size_t)n * 32 + cg * 4) = v;
    }
}

// ---------------- launch ----------------

extern "C" void kernel_launch(void* const* d_in, const int* in_sizes, int n_in,
                              void* d_out, int out_size, void* d_ws, size_t ws_size,
                              hipStream_t stream) {
    const float* x    = (const float*)d_in[0];
    const int*   ei   = (const int*)d_in[1];
    const float* W1   = (const float*)d_in[2];
    const float* a_s1 = (const float*)d_in[3];
    const float* a_d1 = (const float*)d_in[4];
    const float* b1   = (const float*)d_in[5];
    const float* W2   = (const float*)d_in[6];
    const float* a_s2 = (const float*)d_in[7];
    const float* a_d2 = (const float*)d_in[8];
    const float* b2   = (const float*)d_in[9];
    float* out = (float*)d_out;

    const int N = in_sizes[0] / 256;
    const int E = in_sizes[1] / 2;
    const int* srcIdx = ei;
    const int* dstIdx = ei + E;

    char* ws = (char*)d_ws;
    size_t off = 0;
    auto alloc = [&](size_t bytes) {
        void* p = ws + off;
        off += (bytes + 255) & ~(size_t)255;
        return p;
    };
    _Float16* h1   = (_Float16*)alloc((size_t)N * 256 * 2);  // fp16 gather table (layer1)
    _Float16* z    = (_Float16*)alloc((size_t)N * 32 * 2);   // fp16 gather table (layer2)
    float* as1    = (float*)alloc((size_t)N * 16);
    float* ad1    = (float*)alloc((size_t)N * 16);
    float* as2    = (float*)alloc((size_t)N * 4);
    float* ad2    = (float*)alloc((size_t)N * 4);
    short* Wt     = (short*)alloc((size_t)256 * 256 * 2);    // W1^T bf16
    _Float16* W2t = (_Float16*)alloc((size_t)32 * 256 * 2);  // W2^T fp16
    int*   cursor = (int*)alloc((size_t)N * 4);
    int*   col    = (int*)alloc((size_t)N * CAP * 4);        // fixed-capacity buckets

    // prep (weights + bucket init)
    k_prepw<<<256, 256, 0, stream>>>(W1, Wt, W2, W2t, cursor, col, N);

    // fused layer-1 GEMM + edge scatter (R12-verified k-loop-paced atomics)
    const int nGemm = (N + 63) / 64;
    k_gemm1_scatter<<<nGemm, 256, 0, stream>>>(x, Wt, a_s1, a_d1, h1, as1, ad1, N,
                                               srcIdx, dstIdx, cursor, col, E);

    // fused: gather1-softmax + ELU + GEMM2 + alpha2
    k_fuse1<<<(N + 3) / 4, 256, 0, stream>>>(h1, as1, ad1, cursor, col, b1, W2t,
                                             a_s2, a_d2, z, as2, ad2, N);

    // layer 2 gather (burst-MLP form)
    k_gather2<<<(N + 3) / 4, 256, 0, stream>>>(z, as2, ad2, cursor, col, b2, out, N);
}